// Round 7
// baseline (368.827 us; speedup 1.0000x reference)
//
#include <hip/hip_runtime.h>
#include <math.h>

#define D  32
#define BN 16384
#define PP 16

typedef __bf16 bf16x8 __attribute__((ext_vector_type(8)));
typedef float  floatx4 __attribute__((ext_vector_type(4)));

// Weight image (per hop): WIH bf16 128 rows x stride 72 elems; WHH bf16 128 x
// stride 40; bias f32[128] = b_ih+b_hh.
#define WIH_OFF     0
#define WHH_OFF     18432
#define BIAS_OFF    28672
#define IMG_BYTES   29184
#define H_OFF       IMG_BYTES        // H: 64 rows stride 80 B bf16 (5120 B)
#define LDS_BYTES   (IMG_BYTES + 5120)

#define K1 1.44269504088896341f      // log2(e)
#define K2 2.88539008177792681f      // 2*log2(e)

__device__ __forceinline__ float sigf(float x) {
    float e = __builtin_amdgcn_exp2f(-x * K1);
    return __builtin_amdgcn_rcpf(1.0f + e);
}
__device__ __forceinline__ float logsigf(float x) {
    float ax = fabsf(x);
    float l = log1pf(__expf(-ax));
    return (x >= 0.0f) ? -l : x - l;
}

__device__ __forceinline__ bf16x8 cvt8(float4 lo, float4 hi) {
    bf16x8 r = { (__bf16)lo.x, (__bf16)lo.y, (__bf16)lo.z, (__bf16)lo.w,
                 (__bf16)hi.x, (__bf16)hi.y, (__bf16)hi.z, (__bf16)hi.w };
    return r;
}
// 8 floats at tab[row*32 + ak .. +8)  ->  bf16x8
__device__ __forceinline__ bf16x8 load_frag(const float* __restrict__ tab,
                                            int row, int ak) {
    const float4* p = (const float4*)(tab + (size_t)row * D) + (ak >> 2);
    return cvt8(p[0], p[1]);
}

// Build both weight images: blocks 0-7 -> img0, 8-15 -> img1.
__global__ __launch_bounds__(256)
void prep_weights(const float* __restrict__ w_ih0, const float* __restrict__ w_hh0,
                  const float* __restrict__ b_ih0, const float* __restrict__ b_hh0,
                  const float* __restrict__ w_ih1, const float* __restrict__ w_hh1,
                  const float* __restrict__ b_ih1, const float* __restrict__ b_hh1,
                  float* __restrict__ img0, float* __restrict__ img1)
{
    const bool second = blockIdx.x >= 8;
    const float* w_ih = second ? w_ih1 : w_ih0;
    const float* w_hh = second ? w_hh1 : w_hh0;
    const float* b_ih = second ? b_ih1 : b_ih0;
    const float* b_hh = second ? b_hh1 : b_hh0;
    char* base = (char*)(second ? img1 : img0);
    const int t0 = (blockIdx.x & 7) * 256 + threadIdx.x;   // 0..2047
    for (int idx = t0; idx < 8192; idx += 2048) {
        int n = idx >> 6, k = idx & 63;
        ((__bf16*)(base + WIH_OFF))[n * 72 + k] = (__bf16)w_ih[idx];
    }
    for (int idx = t0; idx < 4096; idx += 2048) {
        int n = idx >> 5, k = idx & 31;
        ((__bf16*)(base + WHH_OFF))[n * 40 + k] = (__bf16)w_hh[idx];
    }
    if (t0 < 128)
        ((float*)(base + BIAS_OFF))[t0] = b_ih[t0] + b_hh[t0];
}

// One LSTM step for a wave's 16 pairs. Weights re-read from LDS (broadcast);
// X fragments come in as registers; H round-trips through wave-private LDS.
template<bool FIRST, bool LAST>
__device__ __forceinline__ void lstm_step(
    const char* __restrict__ Wih, const char* __restrict__ Whh, char* __restrict__ Hl,
    bf16x8 ax0, bf16x8 ax1, const float* __restrict__ biasv,
    float* __restrict__ cst, float* __restrict__ hout,
    int bnl, int ak, int am, int wrow, int lane)
{
    bf16x8 ah = {};
    if (!FIRST) ah = *(const bf16x8*)(Hl + am * 80 + ak * 2);

    floatx4 acc[8];
    #pragma unroll
    for (int nt = 0; nt < 8; ++nt) {
        floatx4 v = { biasv[nt], biasv[nt], biasv[nt], biasv[nt] };
        acc[nt] = v;
    }
    #pragma unroll
    for (int nt = 0; nt < 8; ++nt) {
        const int bn = nt * 16 + bnl;
        bf16x8 b0 = *(const bf16x8*)(Wih + bn * 144 + ak * 2);
        bf16x8 b1 = *(const bf16x8*)(Wih + bn * 144 + 64 + ak * 2);
        floatx4 a = acc[nt];
        a = __builtin_amdgcn_mfma_f32_16x16x32_bf16(ax0, b0, a, 0, 0, 0);
        a = __builtin_amdgcn_mfma_f32_16x16x32_bf16(ax1, b1, a, 0, 0, 0);
        if (!FIRST) {
            bf16x8 bh = *(const bf16x8*)(Whh + bn * 80 + ak * 2);
            a = __builtin_amdgcn_mfma_f32_16x16x32_bf16(ah, bh, a, 0, 0, 0);
        }
        acc[nt] = a;
    }

    // C-layout: col = bnl + 16*ng, row(pair) = (lane>>4)*4 + r
    // c = sig(f)*c + sig(i)*tanh(g); h = sig(o)*tanh(c); 4 exp2 + 2 rcp / unit
    #pragma unroll
    for (int ng = 0; ng < 2; ++ng) {
        floatx4 gi = acc[ng], gf = acc[ng + 2], gg = acc[ng + 4], go = acc[ng + 6];
        #pragma unroll
        for (int r = 0; r < 4; ++r) {
            float Ai = 1.0f + __builtin_amdgcn_exp2f(-gi[r] * K1);
            float Af = 1.0f + __builtin_amdgcn_exp2f(-gf[r] * K1);
            float G2 = __builtin_amdgcn_exp2f(gg[r] * K2);
            float Gp = G2 + 1.0f, Gm = G2 - 1.0f;
            float cold = FIRST ? 0.0f : cst[ng * 4 + r];
            float num = cold * Ai * Gp + Gm * Af;
            float c = num * __builtin_amdgcn_rcpf(Af * Ai * Gp);
            cst[ng * 4 + r] = c;
            float Ao = 1.0f + __builtin_amdgcn_exp2f(-go[r] * K1);
            float C2 = __builtin_amdgcn_exp2f(c * K2);
            float h = (C2 - 1.0f) * __builtin_amdgcn_rcpf(Ao * (C2 + 1.0f));
            hout[ng * 4 + r] = h;
            if (!LAST) {
                int pr = wrow + (lane >> 4) * 4 + r;
                *(__bf16*)(Hl + pr * 80 + (ng * 16 + bnl) * 2) = (__bf16)h;
            }
        }
    }
}

// Grid 8192: hop = blockIdx&1, idx = blockIdx>>1. Block = 4 waves; wave w owns
// all 16 p's of batch b = idx*4+w. X fragments prefetched global->reg for all
// steps; weights in LDS; no barriers after init. launch_bounds(256,4): 4
// blocks/CU (16 waves) — latency-bound kernel, occupancy is the lever.
__global__ __launch_bounds__(256, 4)
void hop_mfma(const float* __restrict__ user_table,
              const float* __restrict__ ent_table,
              const float* __restrict__ rel_table,
              const float* __restrict__ img0,
              const float* __restrict__ img1,
              const int*   __restrict__ users,
              const int*   __restrict__ items,
              const int*   __restrict__ lp0,     // (NE,P,3)
              const int*   __restrict__ lp1,     // (NE,P,5)
              float* __restrict__ F0,            // (B,32) sum_p h
              float* __restrict__ F1)
{
    __shared__ __align__(16) char lds[LDS_BYTES];

    const bool second = blockIdx.x & 1;
    const int  idx    = blockIdx.x >> 1;
    const int tid  = threadIdx.x;
    const int lane = tid & 63;
    const int wave = tid >> 6;

    // ---- load weight image into LDS ----------------------------------------
    {
        const float4* g = (const float4*)(second ? img1 : img0);
        float4* l = (float4*)lds;
        #pragma unroll
        for (int i = 0; i < 8; ++i) {
            int k = i * 256 + tid;                 // IMG_BYTES/16 = 1824
            if (k < IMG_BYTES / 16) l[k] = g[k];
        }
    }

    const char* Wih = lds + WIH_OFF;
    const char* Whh = lds + WHH_OFF;
    char* Hl = lds + H_OFF;

    const int bnl  = lane & 15;
    const int ak   = (lane >> 4) * 8;
    const int wrow = wave * 16;
    const int am   = wrow + bnl;                   // A row (pair within block)

    // ---- prefetch all X fragments (global gather -> regs) ------------------
    const int fb   = idx * 4 + wave;               // batch (wave-uniform)
    const int item = items[fb];
    const int user = users[fb];
    const int* __restrict__ il = (second ? lp1 : lp0)
        + ((size_t)item * PP + bnl) * (second ? 5 : 3);

    bf16x8 xa0, xb0, xa1, xb1, xa2 = {}, xb2 = {};
    {
        const int i0 = il[0];
        xa0 = load_frag(user_table, user, ak);
        xb0 = load_frag(ent_table, i0, ak);
        const int i1 = il[1], i2 = il[2];
        xa1 = load_frag(rel_table, i1, ak);
        xb1 = load_frag(ent_table, i2, ak);
        if (second) {
            const int i3 = il[3], i4 = il[4];
            xa2 = load_frag(rel_table, i3, ak);
            xb2 = load_frag(ent_table, i4, ak);
        }
    }

    __syncthreads();   // weight image ready

    float biasv[8];
    {
        const float* bias = (const float*)(lds + BIAS_OFF);
        #pragma unroll
        for (int nt = 0; nt < 8; ++nt) biasv[nt] = bias[nt * 16 + bnl];
    }

    float cst[8], hout[8];
    lstm_step<true, false>(Wih, Whh, Hl, xa0, xb0, biasv, cst, hout, bnl, ak, am, wrow, lane);
    if (!second) {
        lstm_step<false, true>(Wih, Whh, Hl, xa1, xb1, biasv, cst, hout, bnl, ak, am, wrow, lane);
    } else {
        lstm_step<false, false>(Wih, Whh, Hl, xa1, xb1, biasv, cst, hout, bnl, ak, am, wrow, lane);
        lstm_step<false, true >(Wih, Whh, Hl, xa2, xb2, biasv, cst, hout, bnl, ak, am, wrow, lane);
    }

    // ---- sum over the wave's 16 pairs, write F ------------------------------
    float* Fout = second ? F1 : F0;
    #pragma unroll
    for (int ng = 0; ng < 2; ++ng) {
        float v = hout[ng * 4 + 0] + hout[ng * 4 + 1] + hout[ng * 4 + 2] + hout[ng * 4 + 3];
        v += __shfl_xor(v, 16);
        v += __shfl_xor(v, 32);
        if (lane < 16)
            Fout[(size_t)fb * D + ng * 16 + lane] = v;
    }
}

// Per b: emb0=(ent[items]+F0)@W^T+b ; emb1=(emb0+F1)@W^T+b ; score=dot(u,emb1);
// outputs + per-block loss partial. 256 thr = 8 b's x 32 j.
__global__ __launch_bounds__(256)
void chain_score(const float* __restrict__ user_table,
                 const float* __restrict__ ent_table,
                 const float* __restrict__ agg_w,
                 const float* __restrict__ agg_b,
                 const int*   __restrict__ users,
                 const int*   __restrict__ items,
                 const int*   __restrict__ ratings,
                 const float* __restrict__ F0,
                 const float* __restrict__ F1,
                 float* __restrict__ out,
                 float* __restrict__ partials)
{
    __shared__ float s[8][33];
    __shared__ float red[8];
    const int tid = threadIdx.x;
    const int bb  = tid >> 5;
    const int j   = tid & 31;
    const int b   = blockIdx.x * 8 + bb;
    const int it  = items[b];

    s[bb][j] = ent_table[(size_t)it * D + j] + F0[(size_t)b * D + j];
    __syncthreads();
    const float* __restrict__ w = agg_w + (size_t)j * D;
    float e0 = agg_b[j];
    #pragma unroll
    for (int k = 0; k < D; ++k) e0 = fmaf(s[bb][k], w[k], e0);
    __syncthreads();
    s[bb][j] = e0 + F1[(size_t)b * D + j];
    __syncthreads();
    float e1 = agg_b[j];
    #pragma unroll
    for (int k = 0; k < D; ++k) e1 = fmaf(s[bb][k], w[k], e1);

    float prod = user_table[(size_t)users[b] * D + j] * e1;
    #pragma unroll
    for (int m = 1; m < 32; m <<= 1) prod += __shfl_xor(prod, m);
    if (j == 0) {
        out[1 + b]      = sigf(prod);
        out[1 + BN + b] = (float)it;
        float r = (float)ratings[b];
        red[bb] = r * logsigf(prod) + (1.0f - r) * logsigf(-prod);
    }
    __syncthreads();
    if (tid == 0) {
        float t = 0.0f;
        #pragma unroll
        for (int q = 0; q < 8; ++q) t += red[q];
        partials[blockIdx.x] = t;
    }
}

__global__ __launch_bounds__(256)
void loss_kernel(const float* __restrict__ partials, float* __restrict__ out)
{
    __shared__ float red[4];
    const int t = threadIdx.x;
    float v = 0.0f;
    #pragma unroll
    for (int q = 0; q < 8; ++q) v += partials[q * 256 + t];
    #pragma unroll
    for (int m = 1; m < 64; m <<= 1) v += __shfl_xor(v, m);
    if ((t & 63) == 0) red[t >> 6] = v;
    __syncthreads();
    if (t == 0) out[0] = -(red[0] + red[1] + red[2] + red[3]) / (float)BN;
}

extern "C" void kernel_launch(void* const* d_in, const int* in_sizes, int n_in,
                              void* d_out, int out_size, void* d_ws, size_t ws_size,
                              hipStream_t stream)
{
    const float* user_table = (const float*)d_in[0];
    const float* ent_table  = (const float*)d_in[1];
    const float* rel_table  = (const float*)d_in[2];
    const float* w_ih0 = (const float*)d_in[3];
    const float* w_hh0 = (const float*)d_in[4];
    const float* b_ih0 = (const float*)d_in[5];
    const float* b_hh0 = (const float*)d_in[6];
    const float* w_ih1 = (const float*)d_in[7];
    const float* w_hh1 = (const float*)d_in[8];
    const float* b_ih1 = (const float*)d_in[9];
    const float* b_hh1 = (const float*)d_in[10];
    const float* agg_w = (const float*)d_in[11];
    const float* agg_b = (const float*)d_in[12];
    const int* users   = (const int*)d_in[13];
    const int* items   = (const int*)d_in[14];
    const int* ratings = (const int*)d_in[15];
    const int* lp0     = (const int*)d_in[16];
    const int* lp1     = (const int*)d_in[17];
    float* out = (float*)d_out;

    float* ws       = (float*)d_ws;
    float* F0       = ws;                            // B*32
    float* F1       = ws + (size_t)BN * D;           // B*32
    float* partials = ws + 2 * (size_t)BN * D;       // 2048
    float* img0     = ws + 2 * (size_t)BN * D + 2048;
    float* img1     = img0 + IMG_BYTES / 4;

    prep_weights<<<16, 256, 0, stream>>>(w_ih0, w_hh0, b_ih0, b_hh0,
                                         w_ih1, w_hh1, b_ih1, b_hh1, img0, img1);
    hop_mfma<<<8192, 256, 0, stream>>>(
        user_table, ent_table, rel_table, img0, img1,
        users, items, lp0, lp1, F0, F1);
    chain_score<<<BN / 8, 256, 0, stream>>>(
        user_table, ent_table, agg_w, agg_b, users, items, ratings,
        F0, F1, out, partials);
    loss_kernel<<<1, 256, 0, stream>>>(partials, out);
}

// Round 8
// 244.291 us; speedup vs baseline: 1.5098x; 1.5098x over previous
//
#include <hip/hip_runtime.h>
#include <math.h>

#define D  32
#define BN 16384
#define PP 16

typedef __bf16 bf16x8 __attribute__((ext_vector_type(8)));
typedef float  floatx4 __attribute__((ext_vector_type(4)));

// Weight image (per hop): WIH bf16 128 rows x stride 72 elems; WHH bf16 128 x
// stride 40; bias f32[128] = b_ih+b_hh.
#define WIH_OFF     0
#define WHH_OFF     18432
#define BIAS_OFF    28672
#define IMG_BYTES   29184
#define HA_OFF      IMG_BYTES            // H chain A: 64 rows stride 80 B
#define HB_OFF      (IMG_BYTES + 5120)   // H chain B
#define LDS_BYTES   (IMG_BYTES + 10240)

#define K1 1.44269504088896341f      // log2(e)
#define K2 2.88539008177792681f      // 2*log2(e)

__device__ __forceinline__ float sigf(float x) {
    float e = __builtin_amdgcn_exp2f(-x * K1);
    return __builtin_amdgcn_rcpf(1.0f + e);
}
__device__ __forceinline__ float logsigf(float x) {
    float ax = fabsf(x);
    float l = log1pf(__expf(-ax));
    return (x >= 0.0f) ? -l : x - l;
}

__device__ __forceinline__ bf16x8 cvt8(float4 lo, float4 hi) {
    bf16x8 r = { (__bf16)lo.x, (__bf16)lo.y, (__bf16)lo.z, (__bf16)lo.w,
                 (__bf16)hi.x, (__bf16)hi.y, (__bf16)hi.z, (__bf16)hi.w };
    return r;
}
// 8 floats at tab[row*32 + ak .. +8)  ->  bf16x8
__device__ __forceinline__ bf16x8 load_frag(const float* __restrict__ tab,
                                            int row, int ak) {
    const float4* p = (const float4*)(tab + (size_t)row * D) + (ak >> 2);
    return cvt8(p[0], p[1]);
}

// Build both weight images: blocks 0-7 -> img0, 8-15 -> img1.
__global__ __launch_bounds__(256)
void prep_weights(const float* __restrict__ w_ih0, const float* __restrict__ w_hh0,
                  const float* __restrict__ b_ih0, const float* __restrict__ b_hh0,
                  const float* __restrict__ w_ih1, const float* __restrict__ w_hh1,
                  const float* __restrict__ b_ih1, const float* __restrict__ b_hh1,
                  float* __restrict__ img0, float* __restrict__ img1)
{
    const bool second = blockIdx.x >= 8;
    const float* w_ih = second ? w_ih1 : w_ih0;
    const float* w_hh = second ? w_hh1 : w_hh0;
    const float* b_ih = second ? b_ih1 : b_ih0;
    const float* b_hh = second ? b_hh1 : b_hh0;
    char* base = (char*)(second ? img1 : img0);
    const int t0 = (blockIdx.x & 7) * 256 + threadIdx.x;   // 0..2047
    for (int idx = t0; idx < 8192; idx += 2048) {
        int n = idx >> 6, k = idx & 63;
        ((__bf16*)(base + WIH_OFF))[n * 72 + k] = (__bf16)w_ih[idx];
    }
    for (int idx = t0; idx < 4096; idx += 2048) {
        int n = idx >> 5, k = idx & 31;
        ((__bf16*)(base + WHH_OFF))[n * 40 + k] = (__bf16)w_hh[idx];
    }
    if (t0 < 128)
        ((float*)(base + BIAS_OFF))[t0] = b_ih[t0] + b_hh[t0];
}

// One LSTM step for TWO independent chains (2 batches per wave). Weight
// fragments are read from LDS once and feed both chains' MFMAs; the two
// transcendental chains interleave for ILP.
template<bool FIRST, bool LAST>
__device__ __forceinline__ void lstm_step2(
    const char* __restrict__ Wih, const char* __restrict__ Whh,
    char* __restrict__ HlA, char* __restrict__ HlB,
    bf16x8 axA0, bf16x8 axA1, bf16x8 axB0, bf16x8 axB1,
    const float* __restrict__ biasv,
    float* __restrict__ cstA, float* __restrict__ cstB,
    float* __restrict__ houtA, float* __restrict__ houtB,
    int bnl, int ak, int am, int wrow, int lane)
{
    bf16x8 ahA = {}, ahB = {};
    if (!FIRST) {
        ahA = *(const bf16x8*)(HlA + am * 80 + ak * 2);
        ahB = *(const bf16x8*)(HlB + am * 80 + ak * 2);
    }

    floatx4 accA[8], accB[8];
    #pragma unroll
    for (int nt = 0; nt < 8; ++nt) {
        floatx4 v = { biasv[nt], biasv[nt], biasv[nt], biasv[nt] };
        accA[nt] = v;
        accB[nt] = v;
    }
    #pragma unroll
    for (int nt = 0; nt < 8; ++nt) {
        const int bn = nt * 16 + bnl;
        bf16x8 b0 = *(const bf16x8*)(Wih + bn * 144 + ak * 2);
        bf16x8 b1 = *(const bf16x8*)(Wih + bn * 144 + 64 + ak * 2);
        floatx4 a = accA[nt], b = accB[nt];
        a = __builtin_amdgcn_mfma_f32_16x16x32_bf16(axA0, b0, a, 0, 0, 0);
        b = __builtin_amdgcn_mfma_f32_16x16x32_bf16(axB0, b0, b, 0, 0, 0);
        a = __builtin_amdgcn_mfma_f32_16x16x32_bf16(axA1, b1, a, 0, 0, 0);
        b = __builtin_amdgcn_mfma_f32_16x16x32_bf16(axB1, b1, b, 0, 0, 0);
        if (!FIRST) {
            bf16x8 bh = *(const bf16x8*)(Whh + bn * 80 + ak * 2);
            a = __builtin_amdgcn_mfma_f32_16x16x32_bf16(ahA, bh, a, 0, 0, 0);
            b = __builtin_amdgcn_mfma_f32_16x16x32_bf16(ahB, bh, b, 0, 0, 0);
        }
        accA[nt] = a;
        accB[nt] = b;
    }

    // C-layout: col = bnl + 16*ng, row(pair) = (lane>>4)*4 + r
    #pragma unroll
    for (int ng = 0; ng < 2; ++ng) {
        #pragma unroll
        for (int r = 0; r < 4; ++r) {
            #pragma unroll
            for (int cc = 0; cc < 2; ++cc) {
                floatx4* acc = cc ? accB : accA;
                float* cst   = cc ? cstB : cstA;
                float* hout  = cc ? houtB : houtA;
                char*  Hl    = cc ? HlB : HlA;
                float gi = acc[ng][r], gf = acc[ng + 2][r],
                      gg = acc[ng + 4][r], go = acc[ng + 6][r];
                float Ai = 1.0f + __builtin_amdgcn_exp2f(-gi * K1);
                float Af = 1.0f + __builtin_amdgcn_exp2f(-gf * K1);
                float G2 = __builtin_amdgcn_exp2f(gg * K2);
                float Gp = G2 + 1.0f, Gm = G2 - 1.0f;
                float cold = FIRST ? 0.0f : cst[ng * 4 + r];
                float num = cold * Ai * Gp + Gm * Af;
                float c = num * __builtin_amdgcn_rcpf(Af * Ai * Gp);
                cst[ng * 4 + r] = c;
                float Ao = 1.0f + __builtin_amdgcn_exp2f(-go * K1);
                float C2 = __builtin_amdgcn_exp2f(c * K2);
                float h = (C2 - 1.0f) * __builtin_amdgcn_rcpf(Ao * (C2 + 1.0f));
                hout[ng * 4 + r] = h;
                if (!LAST) {
                    int pr = wrow + (lane >> 4) * 4 + r;
                    *(__bf16*)(Hl + pr * 80 + (ng * 16 + bnl) * 2) = (__bf16)h;
                }
            }
        }
    }
}

// Grid 4096: hop = blockIdx&1, idx = blockIdx>>1. Block = 4 waves; wave w owns
// TWO batches (chains A/B): idx*8+w and idx*8+4+w — 2 independent LSTM chains
// per wave for ILP (occupancy is register-capped; TLP can't be raised).
__global__ __launch_bounds__(256, 2)
void hop_mfma(const float* __restrict__ user_table,
              const float* __restrict__ ent_table,
              const float* __restrict__ rel_table,
              const float* __restrict__ img0,
              const float* __restrict__ img1,
              const int*   __restrict__ users,
              const int*   __restrict__ items,
              const int*   __restrict__ lp0,     // (NE,P,3)
              const int*   __restrict__ lp1,     // (NE,P,5)
              float* __restrict__ F0,            // (B,32) sum_p h
              float* __restrict__ F1)
{
    __shared__ __align__(16) char lds[LDS_BYTES];

    const bool second = blockIdx.x & 1;
    const int  idx    = blockIdx.x >> 1;
    const int tid  = threadIdx.x;
    const int lane = tid & 63;
    const int wave = tid >> 6;

    // ---- load weight image into LDS ----------------------------------------
    {
        const float4* g = (const float4*)(second ? img1 : img0);
        float4* l = (float4*)lds;
        #pragma unroll
        for (int i = 0; i < 8; ++i) {
            int k = i * 256 + tid;                 // IMG_BYTES/16 = 1824
            if (k < IMG_BYTES / 16) l[k] = g[k];
        }
    }

    const char* Wih = lds + WIH_OFF;
    const char* Whh = lds + WHH_OFF;
    char* HlA = lds + HA_OFF;
    char* HlB = lds + HB_OFF;

    const int bnl  = lane & 15;
    const int ak   = (lane >> 4) * 8;
    const int wrow = wave * 16;
    const int am   = wrow + bnl;                   // A row (pair within block)

    // ---- prefetch all X fragments for both chains (global gather -> regs) --
    const int fbA = idx * 8 + wave;                // wave-uniform
    const int fbB = idx * 8 + 4 + wave;
    const int L   = second ? 5 : 3;
    const int* __restrict__ ilA = (second ? lp1 : lp0)
        + ((size_t)items[fbA] * PP + bnl) * L;
    const int* __restrict__ ilB = (second ? lp1 : lp0)
        + ((size_t)items[fbB] * PP + bnl) * L;

    bf16x8 xaA0, xbA0, xaA1, xbA1, xaA2 = {}, xbA2 = {};
    bf16x8 xaB0, xbB0, xaB1, xbB1, xaB2 = {}, xbB2 = {};
    {
        xaA0 = load_frag(user_table, users[fbA], ak);
        xaB0 = load_frag(user_table, users[fbB], ak);
        xbA0 = load_frag(ent_table, ilA[0], ak);
        xbB0 = load_frag(ent_table, ilB[0], ak);
        xaA1 = load_frag(rel_table, ilA[1], ak);
        xaB1 = load_frag(rel_table, ilB[1], ak);
        xbA1 = load_frag(ent_table, ilA[2], ak);
        xbB1 = load_frag(ent_table, ilB[2], ak);
        if (second) {
            xaA2 = load_frag(rel_table, ilA[3], ak);
            xaB2 = load_frag(rel_table, ilB[3], ak);
            xbA2 = load_frag(ent_table, ilA[4], ak);
            xbB2 = load_frag(ent_table, ilB[4], ak);
        }
    }

    __syncthreads();   // weight image ready

    float biasv[8];
    {
        const float* bias = (const float*)(lds + BIAS_OFF);
        #pragma unroll
        for (int nt = 0; nt < 8; ++nt) biasv[nt] = bias[nt * 16 + bnl];
    }

    float cstA[8], cstB[8], houtA[8], houtB[8];
    lstm_step2<true, false>(Wih, Whh, HlA, HlB, xaA0, xbA0, xaB0, xbB0,
                            biasv, cstA, cstB, houtA, houtB, bnl, ak, am, wrow, lane);
    if (!second) {
        lstm_step2<false, true>(Wih, Whh, HlA, HlB, xaA1, xbA1, xaB1, xbB1,
                                biasv, cstA, cstB, houtA, houtB, bnl, ak, am, wrow, lane);
    } else {
        lstm_step2<false, false>(Wih, Whh, HlA, HlB, xaA1, xbA1, xaB1, xbB1,
                                 biasv, cstA, cstB, houtA, houtB, bnl, ak, am, wrow, lane);
        lstm_step2<false, true >(Wih, Whh, HlA, HlB, xaA2, xbA2, xaB2, xbB2,
                                 biasv, cstA, cstB, houtA, houtB, bnl, ak, am, wrow, lane);
    }

    // ---- sum over each chain's 16 pairs, write F ----------------------------
    float* Fout = second ? F1 : F0;
    #pragma unroll
    for (int ng = 0; ng < 2; ++ng) {
        float vA = houtA[ng * 4 + 0] + houtA[ng * 4 + 1] + houtA[ng * 4 + 2] + houtA[ng * 4 + 3];
        float vB = houtB[ng * 4 + 0] + houtB[ng * 4 + 1] + houtB[ng * 4 + 2] + houtB[ng * 4 + 3];
        vA += __shfl_xor(vA, 16);
        vA += __shfl_xor(vA, 32);
        vB += __shfl_xor(vB, 16);
        vB += __shfl_xor(vB, 32);
        if (lane < 16) {
            Fout[(size_t)fbA * D + ng * 16 + lane] = vA;
            Fout[(size_t)fbB * D + ng * 16 + lane] = vB;
        }
    }
}

// Per b: emb0=(ent[items]+F0)@W^T+b ; emb1=(emb0+F1)@W^T+b ; score=dot(u,emb1);
// outputs + per-block loss partial. 256 thr = 8 b's x 32 j.
__global__ __launch_bounds__(256)
void chain_score(const float* __restrict__ user_table,
                 const float* __restrict__ ent_table,
                 const float* __restrict__ agg_w,
                 const float* __restrict__ agg_b,
                 const int*   __restrict__ users,
                 const int*   __restrict__ items,
                 const int*   __restrict__ ratings,
                 const float* __restrict__ F0,
                 const float* __restrict__ F1,
                 float* __restrict__ out,
                 float* __restrict__ partials)
{
    __shared__ float s[8][33];
    __shared__ float red[8];
    const int tid = threadIdx.x;
    const int bb  = tid >> 5;
    const int j   = tid & 31;
    const int b   = blockIdx.x * 8 + bb;
    const int it  = items[b];

    s[bb][j] = ent_table[(size_t)it * D + j] + F0[(size_t)b * D + j];
    __syncthreads();
    const float* __restrict__ w = agg_w + (size_t)j * D;
    float e0 = agg_b[j];
    #pragma unroll
    for (int k = 0; k < D; ++k) e0 = fmaf(s[bb][k], w[k], e0);
    __syncthreads();
    s[bb][j] = e0 + F1[(size_t)b * D + j];
    __syncthreads();
    float e1 = agg_b[j];
    #pragma unroll
    for (int k = 0; k < D; ++k) e1 = fmaf(s[bb][k], w[k], e1);

    float prod = user_table[(size_t)users[b] * D + j] * e1;
    #pragma unroll
    for (int m = 1; m < 32; m <<= 1) prod += __shfl_xor(prod, m);
    if (j == 0) {
        out[1 + b]      = sigf(prod);
        out[1 + BN + b] = (float)it;
        float r = (float)ratings[b];
        red[bb] = r * logsigf(prod) + (1.0f - r) * logsigf(-prod);
    }
    __syncthreads();
    if (tid == 0) {
        float t = 0.0f;
        #pragma unroll
        for (int q = 0; q < 8; ++q) t += red[q];
        partials[blockIdx.x] = t;
    }
}

__global__ __launch_bounds__(256)
void loss_kernel(const float* __restrict__ partials, float* __restrict__ out)
{
    __shared__ float red[4];
    const int t = threadIdx.x;
    float v = 0.0f;
    #pragma unroll
    for (int q = 0; q < 8; ++q) v += partials[q * 256 + t];
    #pragma unroll
    for (int m = 1; m < 64; m <<= 1) v += __shfl_xor(v, m);
    if ((t & 63) == 0) red[t >> 6] = v;
    __syncthreads();
    if (t == 0) out[0] = -(red[0] + red[1] + red[2] + red[3]) / (float)BN;
}

extern "C" void kernel_launch(void* const* d_in, const int* in_sizes, int n_in,
                              void* d_out, int out_size, void* d_ws, size_t ws_size,
                              hipStream_t stream)
{
    const float* user_table = (const float*)d_in[0];
    const float* ent_table  = (const float*)d_in[1];
    const float* rel_table  = (const float*)d_in[2];
    const float* w_ih0 = (const float*)d_in[3];
    const float* w_hh0 = (const float*)d_in[4];
    const float* b_ih0 = (const float*)d_in[5];
    const float* b_hh0 = (const float*)d_in[6];
    const float* w_ih1 = (const float*)d_in[7];
    const float* w_hh1 = (const float*)d_in[8];
    const float* b_ih1 = (const float*)d_in[9];
    const float* b_hh1 = (const float*)d_in[10];
    const float* agg_w = (const float*)d_in[11];
    const float* agg_b = (const float*)d_in[12];
    const int* users   = (const int*)d_in[13];
    const int* items   = (const int*)d_in[14];
    const int* ratings = (const int*)d_in[15];
    const int* lp0     = (const int*)d_in[16];
    const int* lp1     = (const int*)d_in[17];
    float* out = (float*)d_out;

    float* ws       = (float*)d_ws;
    float* F0       = ws;                            // B*32
    float* F1       = ws + (size_t)BN * D;           // B*32
    float* partials = ws + 2 * (size_t)BN * D;       // 2048
    float* img0     = ws + 2 * (size_t)BN * D + 2048;
    float* img1     = img0 + IMG_BYTES / 4;

    prep_weights<<<16, 256, 0, stream>>>(w_ih0, w_hh0, b_ih0, b_hh0,
                                         w_ih1, w_hh1, b_ih1, b_hh1, img0, img1);
    hop_mfma<<<4096, 256, 0, stream>>>(
        user_table, ent_table, rel_table, img0, img1,
        users, items, lp0, lp1, F0, F1);
    chain_score<<<BN / 8, 256, 0, stream>>>(
        user_table, ent_table, agg_w, agg_b, users, items, ratings,
        F0, F1, out, partials);
    loss_kernel<<<1, 256, 0, stream>>>(partials, out);
}